// Round 10
// baseline (204.849 us; speedup 1.0000x reference)
//
#include <hip/hip_runtime.h>
#include <hip/hip_bf16.h>
#include <hip/hip_cooperative_groups.h>

namespace cg = cooperative_groups;

// EdgeConv forward, Round 10: ONE cooperative launch, grid sync between phases.
//   phase 1: Y8/scale = rowquant_i8(X @ W2^T), Bb = bf16(bias + X @ (W1-W2)^T)
//   phase 2: out[i] = relu(Bb_i + max_{e} scale[j_e] * Y8[j_e])
// Valid: max over edges is elementwise, base_i edge-invariant, relu monotone,
// DEG=16 edges contiguous per node (dst = repeat(arange(N),16)).
//
// R8/R9 evidence: halving gather bytes + L2-residency moved nothing ->
// per-LAUNCH fixed cost (~8-12us: dispatch/drain/cold-I$ after the 256MB
// poison fill) dominates the controllable budget. R10 cuts launches 2->1 via
// hipLaunchCooperativeKernel (harness-supported per guide) + grid.sync().
// __threadfence() before sync for cross-XCD visibility of Y8/SC/Bb.
//
// Fragment layouts (m89/m91-verified):
//   A[m=lane&15][k=(lane>>4)*8+j], B[k=(lane>>4)*8+j][n=lane&15],
//   D: col=lane&15, row=(lane>>4)*4+reg

#define DEG 16
#define C 64

typedef __attribute__((ext_vector_type(8))) short s16x8;
typedef __attribute__((ext_vector_type(4))) float f32x4;

__device__ __forceinline__ unsigned pk2(float lo, float hi) {
    __hip_bfloat162 h = __float22bfloat162_rn(make_float2(lo, hi));
    union { __hip_bfloat162 h; unsigned u; } c; c.h = h;
    return c.u;
}
__device__ __forceinline__ s16x8 cvt_frag(f32x4 a, f32x4 b) {
    union { unsigned u[4]; s16x8 v; } r;
    r.u[0] = pk2(a[0], a[1]); r.u[1] = pk2(a[2], a[3]);
    r.u[2] = pk2(b[0], b[1]); r.u[3] = pk2(b[2], b[3]);
    return r.v;
}
__device__ __forceinline__ float bf2f(unsigned short u) {
    union { unsigned u; float f; } c; c.u = ((unsigned)u) << 16;
    return c.f;
}

// ---- phase 1: dense GEMM -> Y8/scale (i8) + Bb (bf16), grid-stride ----
__device__ __forceinline__ void phase1_body(
    const float* __restrict__ x, const float* __restrict__ W,
    const float* __restrict__ bias,
    signed char* __restrict__ Y8, float* __restrict__ SC,
    unsigned short* __restrict__ Bb,
    int n_groups, int n_nodes, int gwave, int nwaves)
{
    const int lane = threadIdx.x & 63;
    const int col  = lane & 15;
    const int quad = lane >> 4;

    // W fragments, built once per wave (W is 32KB, L2-hot)
    s16x8 bd[4][2], b2[4][2];
    #pragma unroll
    for (int nt = 0; nt < 4; ++nt) {
        const float* wrow = W + (nt * 16 + col) * (2 * C);
        #pragma unroll
        for (int ks = 0; ks < 2; ++ks) {
            const int k0 = ks * 32 + quad * 8;
            f32x4 w1a = *(const f32x4*)(wrow + k0);
            f32x4 w1b = *(const f32x4*)(wrow + k0 + 4);
            f32x4 w2a = *(const f32x4*)(wrow + C + k0);
            f32x4 w2b = *(const f32x4*)(wrow + C + k0 + 4);
            b2[nt][ks] = cvt_frag(w2a, w2b);
            f32x4 da, db;
            #pragma unroll
            for (int j = 0; j < 4; ++j) { da[j] = w1a[j] - w2a[j]; db[j] = w1b[j] - w2b[j]; }
            bd[nt][ks] = cvt_frag(da, db);
        }
    }
    float bv[4];
    #pragma unroll
    for (int nt = 0; nt < 4; ++nt) bv[nt] = bias[nt * 16 + col];

    for (int group = gwave; group < n_groups; group += nwaves) {
        const int node0 = group * 16;
        int arow = node0 + col;
        if (arow >= n_nodes) arow = n_nodes - 1;  // tail clamp (N%16==0 here)
        const float* xp = x + (size_t)arow * C + quad * 8;
        s16x8 xi0 = cvt_frag(*(const f32x4*)xp, *(const f32x4*)(xp + 4));
        s16x8 xi1 = cvt_frag(*(const f32x4*)(xp + 32), *(const f32x4*)(xp + 36));

        f32x4 yD[4], bD[4];
        #pragma unroll
        for (int nt = 0; nt < 4; ++nt) {
            bD[nt] = (f32x4){bv[nt], bv[nt], bv[nt], bv[nt]};
            yD[nt] = (f32x4){0.f, 0.f, 0.f, 0.f};
        }
        #pragma unroll
        for (int nt = 0; nt < 4; ++nt) {
            yD[nt] = __builtin_amdgcn_mfma_f32_16x16x32_bf16(xi0, b2[nt][0], yD[nt], 0, 0, 0);
            yD[nt] = __builtin_amdgcn_mfma_f32_16x16x32_bf16(xi1, b2[nt][1], yD[nt], 0, 0, 0);
            bD[nt] = __builtin_amdgcn_mfma_f32_16x16x32_bf16(xi0, bd[nt][0], bD[nt], 0, 0, 0);
            bD[nt] = __builtin_amdgcn_mfma_f32_16x16x32_bf16(xi1, bd[nt][1], bD[nt], 0, 0, 0);
        }

        // D layout: row = quad*4 + r, col = nt*16 + col
        #pragma unroll
        for (int r = 0; r < 4; ++r) {
            int row = node0 + quad * 4 + r;
            if (row >= n_nodes) row = n_nodes - 1;
            // per-row max|y|: in-lane over nt, then across the quad's 16 lanes
            float am = fmaxf(fmaxf(fabsf(yD[0][r]), fabsf(yD[1][r])),
                             fmaxf(fabsf(yD[2][r]), fabsf(yD[3][r])));
            am = fmaxf(am, __shfl_xor(am, 1));
            am = fmaxf(am, __shfl_xor(am, 2));
            am = fmaxf(am, __shfl_xor(am, 4));
            am = fmaxf(am, __shfl_xor(am, 8));
            const float inv = am > 0.f ? 127.0f / am : 0.f;
            #pragma unroll
            for (int nt = 0; nt < 4; ++nt) {
                int q = __float2int_rn(yD[nt][r] * inv);
                q = q > 127 ? 127 : (q < -127 ? -127 : q);
                Y8[(size_t)row * C + nt * 16 + col] = (signed char)q;
                Bb[(size_t)row * C + nt * 16 + col] =
                    (unsigned short)(pk2(bD[nt][r], 0.f) & 0xFFFF);
            }
            if (col == 0) SC[row] = am * (1.0f / 127.0f);
        }
    }
}

// ---- phase 2: gather-max, one wave per node, grid-stride, pipelined ----
__device__ __forceinline__ void phase2_body(
    const signed char* __restrict__ Y8, const float* __restrict__ SC,
    const unsigned short* __restrict__ Bb, const int* __restrict__ src,
    float* __restrict__ out, int n_nodes, int gwave, int nwaves)
{
    const int lane = threadIdx.x & 63;
    int i = gwave;
    if (i >= n_nodes) return;

    int   jreg = (lane < DEG) ? src[i * DEG + lane] : 0;
    float bs   = bf2f(Bb[(size_t)i * C + lane]);
    float scl  = (lane < DEG) ? SC[jreg] : 0.f;  // one load; bcast via shfl

    while (true) {
        const int inext = i + nwaves;
        int jn = 0; float bn = 0.f;
        if (inext < n_nodes) {  // prefetch next node's state under the gathers
            jn = (lane < DEG) ? src[inext * DEG + lane] : 0;
            bn = bf2f(Bb[(size_t)inext * C + lane]);
        }

        signed char v[DEG];
        #pragma unroll
        for (int e = 0; e < DEG; ++e) {
            int j = __shfl(jreg, e);
            v[e] = Y8[(size_t)j * C + lane];  // 64 lanes x 1B = one 64B line
        }
        float m = -3.0e38f;
        #pragma unroll
        for (int e = 0; e < DEG; ++e) {
            float s = __shfl(scl, e);
            m = fmaxf(m, (float)v[e] * s);
        }
        out[(size_t)i * C + lane] = fmaxf(bs + m, 0.0f);

        if (inext >= n_nodes) break;
        i = inext; jreg = jn; bs = bn;
        scl = (lane < DEG) ? SC[jreg] : 0.f;
    }
}

// ---- single cooperative kernel ----
__global__ __launch_bounds__(256, 3) void edgeconv_coop(
    const float* __restrict__ x, const int* __restrict__ src,
    const float* __restrict__ W, const float* __restrict__ bias,
    signed char* __restrict__ Y8, float* __restrict__ SC,
    unsigned short* __restrict__ Bb, float* __restrict__ out,
    int n_groups, int n_nodes)
{
    const int gwave  = (int)((blockIdx.x * blockDim.x + threadIdx.x) >> 6);
    const int nwaves = (int)((gridDim.x * blockDim.x) >> 6);
    phase1_body(x, W, bias, Y8, SC, Bb, n_groups, n_nodes, gwave, nwaves);
    __threadfence();            // device-scope release of Y8/SC/Bb (cross-XCD)
    cg::this_grid().sync();
    phase2_body(Y8, SC, Bb, src, out, n_nodes, gwave, nwaves);
}

// ---- two-kernel fallback (if cooperative launch is refused) ----
__global__ __launch_bounds__(256, 3) void k_phase1(
    const float* __restrict__ x, const float* __restrict__ W,
    const float* __restrict__ bias, signed char* __restrict__ Y8,
    float* __restrict__ SC, unsigned short* __restrict__ Bb,
    int n_groups, int n_nodes)
{
    const int gwave  = (int)((blockIdx.x * blockDim.x + threadIdx.x) >> 6);
    const int nwaves = (int)((gridDim.x * blockDim.x) >> 6);
    phase1_body(x, W, bias, Y8, SC, Bb, n_groups, n_nodes, gwave, nwaves);
}
__global__ __launch_bounds__(256, 6) void k_phase2(
    const signed char* __restrict__ Y8, const float* __restrict__ SC,
    const unsigned short* __restrict__ Bb, const int* __restrict__ src,
    float* __restrict__ out, int n_nodes)
{
    const int gwave  = (int)((blockIdx.x * blockDim.x + threadIdx.x) >> 6);
    const int nwaves = (int)((gridDim.x * blockDim.x) >> 6);
    phase2_body(Y8, SC, Bb, src, out, n_nodes, gwave, nwaves);
}

// ---- fallback (ws too small): R3-proven fused kernel ----
__global__ __launch_bounds__(256, 2) void edgeconv_fallback(
    const float* __restrict__ x, const int* __restrict__ src,
    const float* __restrict__ W, const float* __restrict__ bias,
    float* __restrict__ out, int n_groups)
{
    const int lane = threadIdx.x & 63, wave = threadIdx.x >> 6;
    const int col = lane & 15, quad = lane >> 4;
    int group = blockIdx.x * 4 + wave;
    if (group >= n_groups) group = n_groups - 1;

    auto frag = [&](int row, int koff) {
        const float* p = x + row * C + koff;
        return cvt_frag(*(const f32x4*)p, *(const f32x4*)(p + 4));
    };

    s16x8 b2[4][2];
    f32x4 baseD[4];
    {
        s16x8 bd[4][2];
        #pragma unroll
        for (int nt = 0; nt < 4; ++nt) {
            const float* wrow = W + (nt * 16 + col) * (2 * C);
            #pragma unroll
            for (int ks = 0; ks < 2; ++ks) {
                const int k0 = ks * 32 + quad * 8;
                f32x4 w1a = *(const f32x4*)(wrow + k0);
                f32x4 w1b = *(const f32x4*)(wrow + k0 + 4);
                f32x4 w2a = *(const f32x4*)(wrow + C + k0);
                f32x4 w2b = *(const f32x4*)(wrow + C + k0 + 4);
                b2[nt][ks] = cvt_frag(w2a, w2b);
                f32x4 da, db;
                #pragma unroll
                for (int j = 0; j < 4; ++j) { da[j] = w1a[j] - w2a[j]; db[j] = w1b[j] - w2b[j]; }
                bd[nt][ks] = cvt_frag(da, db);
            }
        }
        #pragma unroll
        for (int nt = 0; nt < 4; ++nt) {
            float bvv = bias[nt * 16 + col];
            baseD[nt] = (f32x4){bvv, bvv, bvv, bvv};
        }
        const int nrow = group * 16 + col;
        s16x8 xi0 = frag(nrow, quad * 8), xi1 = frag(nrow, 32 + quad * 8);
        #pragma unroll
        for (int nt = 0; nt < 4; ++nt) {
            baseD[nt] = __builtin_amdgcn_mfma_f32_16x16x32_bf16(xi0, bd[nt][0], baseD[nt], 0, 0, 0);
            baseD[nt] = __builtin_amdgcn_mfma_f32_16x16x32_bf16(xi1, bd[nt][1], baseD[nt], 0, 0, 0);
        }
    }
    int idx[16];
    #pragma unroll
    for (int n = 0; n < 16; ++n) idx[n] = src[group * 256 + n * DEG + col];
    s16x8 xa[3][2];
    #pragma unroll
    for (int p = 0; p < 2; ++p) {
        xa[p][0] = frag(idx[p], quad * 8); xa[p][1] = frag(idx[p], 32 + quad * 8);
    }
    #pragma unroll
    for (int n = 0; n < 16; ++n) {
        if (n + 2 < 16) {
            xa[(n + 2) % 3][0] = frag(idx[n + 2], quad * 8);
            xa[(n + 2) % 3][1] = frag(idx[n + 2], 32 + quad * 8);
        }
        const int slane = ((n >> 2) << 4) | col;
        f32x4 acc[4];
        #pragma unroll
        for (int nt = 0; nt < 4; ++nt) {
            float bb = __shfl(baseD[nt][n & 3], slane);
            acc[nt] = (f32x4){bb, bb, bb, bb};
        }
        #pragma unroll
        for (int nt = 0; nt < 4; ++nt) {
            acc[nt] = __builtin_amdgcn_mfma_f32_16x16x32_bf16(xa[n % 3][0], b2[nt][0], acc[nt], 0, 0, 0);
            acc[nt] = __builtin_amdgcn_mfma_f32_16x16x32_bf16(xa[n % 3][1], b2[nt][1], acc[nt], 0, 0, 0);
        }
        float m[4];
        #pragma unroll
        for (int nt = 0; nt < 4; ++nt) {
            float t = fmaxf(fmaxf(acc[nt][0], acc[nt][1]),
                            fmaxf(acc[nt][2], acc[nt][3]));
            t = fmaxf(t, __shfl_xor(t, 16));
            t = fmaxf(t, __shfl_xor(t, 32));
            m[nt] = t;
        }
        float r = quad == 0 ? m[0] : quad == 1 ? m[1] : quad == 2 ? m[2] : m[3];
        out[(group * 16 + n) * C + lane] = fmaxf(r, 0.0f);
    }
}

extern "C" void kernel_launch(void* const* d_in, const int* in_sizes, int n_in,
                              void* d_out, int out_size, void* d_ws, size_t ws_size,
                              hipStream_t stream) {
    const float* x    = (const float*)d_in[0];
    const int*   src  = (const int*)  d_in[1];   // row 0 of edge_index
    const float* W    = (const float*)d_in[3];
    const float* b    = (const float*)d_in[4];
    float*       out  = (float*)d_out;

    const int n_nodes = in_sizes[0] / C;  // 50000
    const int n_groups = (n_nodes + 15) / 16;  // 3125

    // ws: [ Y8 i8 : N*C ][ SC f32 : N ][ Bb bf16 : N*C ]
    const size_t y8_bytes = (size_t)n_nodes * C;
    const size_t sc_bytes = (size_t)n_nodes * sizeof(float);
    const size_t bb_bytes = (size_t)n_nodes * C * sizeof(unsigned short);

    if (ws_size >= y8_bytes + sc_bytes + bb_bytes) {
        signed char*    Y8 = (signed char*)d_ws;
        float*          SC = (float*)((char*)d_ws + y8_bytes);
        unsigned short* Bb = (unsigned short*)((char*)d_ws + y8_bytes + sc_bytes);

        int maxB = 0;
        hipError_t oe = hipOccupancyMaxActiveBlocksPerMultiprocessor(
            &maxB, edgeconv_coop, 256, 0);
        int grid = (oe == hipSuccess && maxB > 0) ? maxB * 256 : 512;
        if (grid > 1024) grid = 1024;

        void* args[] = {(void*)&x, (void*)&src, (void*)&W, (void*)&b,
                        (void*)&Y8, (void*)&SC, (void*)&Bb, (void*)&out,
                        (void*)&n_groups, (void*)&n_nodes};
        hipError_t e = hipLaunchCooperativeKernel(
            edgeconv_coop, dim3(grid), dim3(256), args, 0, stream);
        if (e != hipSuccess) {
            // two-kernel fallback (R9 structure)
            k_phase1<<<(n_groups + 3) / 4, 256, 0, stream>>>(
                x, W, b, Y8, SC, Bb, n_groups, n_nodes);
            k_phase2<<<(n_nodes + 3) / 4, 256, 0, stream>>>(
                Y8, SC, Bb, src, out, n_nodes);
        }
    } else {
        edgeconv_fallback<<<(n_groups + 3) / 4, 256, 0, stream>>>(
            x, src, W, b, out, n_groups);
    }
}

// Round 11
// 98.929 us; speedup vs baseline: 2.0707x; 2.0707x over previous
//
#include <hip/hip_runtime.h>

// EdgeConv forward via MFMA (bf16 inputs, fp32 accumulate). Round 11:
// exact revert to the Round-6 configuration (best measured: 97.8 us).
//
// out[i] = max_j relu(W @ concat(x_i, x_j - x_i) + b), DEG=16 contiguous/node.
// Split W=[W1|W2]: msg = base + x_j.W2^T, base = b + x_i.(W1-W2)^T.
//
// Structure-space evidence (R4..R10): NPW=8 fused MFMA edge kernel + bf16
// prep beats factored-GEMM (R8/R9), single-kernel fp32-gather (R7), and
// cooperative single-launch (R10, 2x regression). dur ~= ~67us harness-fixed
// + prep ~8us + edge ~20us; edge kernel sits at the random-line gather
// service floor (102 MB logical, ~5 TB/s effective mixed L2/L3).
//
// Fragment layouts (m89/m91-verified):
//   A[m=lane&15][k=(lane>>4)*8+j] -> bytes at row*C + ks*32 + quad*8
//   B[k=(lane>>4)*8+j][n=lane&15],  D: col=lane&15, row=(lane>>4)*4+reg

#define DEG 16
#define C 64
#define NPW 8    // nodes per wave
#define WPB 4    // waves per block

typedef __attribute__((ext_vector_type(8))) short s16x8;  // 8 bf16 = 4 VGPRs
typedef __attribute__((ext_vector_type(4))) float f32x4;  // MFMA C/D

__device__ __forceinline__ unsigned short f2bf(float f) {
    union { float f; unsigned u; } v; v.f = f;
    unsigned u = v.u + 0x7FFFu + ((v.u >> 16) & 1u);  // round-nearest-even
    return (unsigned short)(u >> 16);
}

// ws layout (ushorts): [ x_bf16 : N*C ][ wfrag table : 16*64*8 ]
// wfrag slot f = which*8 + nt*2 + ks (0=bd=(W1-W2)^T, 1=b2=W2^T); lane frag at (f*64+l)*8.

__global__ __launch_bounds__(256) void prep(const float* __restrict__ x,
                                            const float* __restrict__ W,
                                            unsigned short* __restrict__ ws_u,
                                            int n4) {
    int i = blockIdx.x * blockDim.x + threadIdx.x;
    if (i < n4) {
        f32x4 v = ((const f32x4*)x)[i];
        ushort4 o;
        o.x = f2bf(v[0]); o.y = f2bf(v[1]); o.z = f2bf(v[2]); o.w = f2bf(v[3]);
        ((ushort4*)ws_u)[i] = o;
    }
    if (blockIdx.x == 0 && threadIdx.x < 64) {
        const int lane = threadIdx.x, col = lane & 15, quad = lane >> 4;
        unsigned short* wf = ws_u + (size_t)n4 * 4;
        #pragma unroll
        for (int nt = 0; nt < 4; ++nt) {
            const float* wrow = W + (nt * 16 + col) * (2 * C);
            #pragma unroll
            for (int ks = 0; ks < 2; ++ks) {
                const int k0 = ks * 32 + quad * 8;
                f32x4 w1a = *(const f32x4*)(wrow + k0);
                f32x4 w1b = *(const f32x4*)(wrow + k0 + 4);
                f32x4 w2a = *(const f32x4*)(wrow + C + k0);
                f32x4 w2b = *(const f32x4*)(wrow + C + k0 + 4);
                s16x8 t2, td;
                #pragma unroll
                for (int j = 0; j < 4; ++j) {
                    t2[j]     = (short)f2bf(w2a[j]);
                    t2[j + 4] = (short)f2bf(w2b[j]);
                    td[j]     = (short)f2bf(w1a[j] - w2a[j]);
                    td[j + 4] = (short)f2bf(w1b[j] - w2b[j]);
                }
                *(s16x8*)(wf + (((0 * 8) + nt * 2 + ks) * 64 + lane) * 8) = td;
                *(s16x8*)(wf + (((1 * 8) + nt * 2 + ks) * 64 + lane) * 8) = t2;
            }
        }
    }
}

__global__ __launch_bounds__(256, 3) void edgeconv_mfma(
    const unsigned short* __restrict__ xb,    // [N,64] bf16 (in ws)
    const int* __restrict__ src,              // [E] edge sources
    const float* __restrict__ bias,           // [64]
    float* __restrict__ out,                  // [N,64]
    int n_groups, int n_nodes)
{
    const int lane = threadIdx.x & 63;
    const int wave = threadIdx.x >> 6;
    const int col  = lane & 15;
    const int quad = lane >> 4;
    int group = blockIdx.x * WPB + wave;
    if (group >= n_groups) group = n_groups - 1;  // dup work, identical writes
    const int node0 = group * NPW;

    // ---- 1. edge indices (head of the longest dependent chain) ----
    int idx[NPW];
    #pragma unroll
    for (int n = 0; n < NPW; ++n)
        idx[n] = src[node0 * DEG + n * DEG + col];  // lane's A-row = edge col

    // ---- 2. W fragments from the prebuilt table (coalesced, L2-hot) ----
    const unsigned short* wf = xb + (size_t)n_nodes * C;
    s16x8 bd[4][2], b2[4][2];
    #pragma unroll
    for (int nt = 0; nt < 4; ++nt)
        #pragma unroll
        for (int ks = 0; ks < 2; ++ks) {
            bd[nt][ks] = *(const s16x8*)(wf + ((nt * 2 + ks) * 64 + lane) * 8);
            b2[nt][ks] = *(const s16x8*)(wf + ((8 + nt * 2 + ks) * 64 + lane) * 8);
        }

    // ---- 3. stage 1: base = bias + XI @ (W1-W2)^T ----
    // A rows 0..7 = the wave's 8 nodes (rows 8..15 dup via col&7: harmless).
    const int xirow = node0 + (col & 7);
    s16x8 xi0 = *(const s16x8*)(xb + xirow * C + quad * 8);
    s16x8 xi1 = *(const s16x8*)(xb + xirow * C + 32 + quad * 8);
    f32x4 baseD[4];
    #pragma unroll
    for (int nt = 0; nt < 4; ++nt) {
        float bv = bias[nt * 16 + col];
        baseD[nt] = (f32x4){bv, bv, bv, bv};
    }
    #pragma unroll
    for (int nt = 0; nt < 4; ++nt) {
        baseD[nt] = __builtin_amdgcn_mfma_f32_16x16x32_bf16(xi0, bd[nt][0], baseD[nt], 0, 0, 0);
        baseD[nt] = __builtin_amdgcn_mfma_f32_16x16x32_bf16(xi1, bd[nt][1], baseD[nt], 0, 0, 0);
    }
    // base[node n][nt*16+c]: lane ((n>>2)<<4)|c, reg n&3.

    // ---- 4. issue ALL gathers (16 outstanding dwordx4 per lane) ----
    s16x8 xa[NPW][2];
    #pragma unroll
    for (int n = 0; n < NPW; ++n) {
        xa[n][0] = *(const s16x8*)(xb + idx[n] * C + quad * 8);
        xa[n][1] = *(const s16x8*)(xb + idx[n] * C + 32 + quad * 8);
    }

    // ---- 5. per-node: MSG = base + XJ @ W2^T, column-max, relu, store ----
    #pragma unroll
    for (int n = 0; n < NPW; ++n) {
        const int slane = ((n >> 2) << 4) | col;
        f32x4 acc[4];
        #pragma unroll
        for (int nt = 0; nt < 4; ++nt) {
            float bb = __shfl(baseD[nt][n & 3], slane);  // base[n][nt*16+col]
            acc[nt] = (f32x4){bb, bb, bb, bb};
        }
        #pragma unroll
        for (int nt = 0; nt < 4; ++nt) {
            acc[nt] = __builtin_amdgcn_mfma_f32_16x16x32_bf16(xa[n][0], b2[nt][0], acc[nt], 0, 0, 0);
            acc[nt] = __builtin_amdgcn_mfma_f32_16x16x32_bf16(xa[n][1], b2[nt][1], acc[nt], 0, 0, 0);
        }
        // max over edges (rows): 4 regs in-lane, then cross-quad shfl_xor.
        float m[4];
        #pragma unroll
        for (int nt = 0; nt < 4; ++nt) {
            float t = fmaxf(fmaxf(acc[nt][0], acc[nt][1]),
                            fmaxf(acc[nt][2], acc[nt][3]));
            t = fmaxf(t, __shfl_xor(t, 16));
            t = fmaxf(t, __shfl_xor(t, 32));
            m[nt] = t;
        }
        float r = quad == 0 ? m[0] : quad == 1 ? m[1] : quad == 2 ? m[2] : m[3];
        r = fmaxf(r, 0.0f);  // relu (monotone: fold after max)
        out[(node0 + n) * C + lane] = r;  // coalesced 256B/node
    }
}

// Fallback (no ws): R3-proven kernel, NPW=16, in-wave W build, fp32 gather.
__global__ __launch_bounds__(256, 2) void edgeconv_fallback(
    const float* __restrict__ x, const int* __restrict__ src,
    const float* __restrict__ W, const float* __restrict__ bias,
    float* __restrict__ out, int n_groups)
{
    const int lane = threadIdx.x & 63, wave = threadIdx.x >> 6;
    const int col = lane & 15, quad = lane >> 4;
    int group = blockIdx.x * WPB + wave;
    if (group >= n_groups) group = n_groups - 1;

    auto frag = [&](int row, int koff) {
        const float* p = x + row * C + koff;
        f32x4 a = *(const f32x4*)p, b = *(const f32x4*)(p + 4);
        s16x8 r;
        #pragma unroll
        for (int j = 0; j < 4; ++j) {
            r[j] = (short)f2bf(a[j]); r[j + 4] = (short)f2bf(b[j]);
        }
        return r;
    };

    s16x8 b2[4][2];
    f32x4 baseD[4];
    {
        s16x8 bd[4][2];
        #pragma unroll
        for (int nt = 0; nt < 4; ++nt) {
            const float* wrow = W + (nt * 16 + col) * (2 * C);
            #pragma unroll
            for (int ks = 0; ks < 2; ++ks) {
                const int k0 = ks * 32 + quad * 8;
                f32x4 w1a = *(const f32x4*)(wrow + k0);
                f32x4 w1b = *(const f32x4*)(wrow + k0 + 4);
                f32x4 w2a = *(const f32x4*)(wrow + C + k0);
                f32x4 w2b = *(const f32x4*)(wrow + C + k0 + 4);
                s16x8 t2, td;
                #pragma unroll
                for (int j = 0; j < 4; ++j) {
                    t2[j] = (short)f2bf(w2a[j]); t2[j + 4] = (short)f2bf(w2b[j]);
                    td[j] = (short)f2bf(w1a[j] - w2a[j]);
                    td[j + 4] = (short)f2bf(w1b[j] - w2b[j]);
                }
                b2[nt][ks] = t2; bd[nt][ks] = td;
            }
        }
        #pragma unroll
        for (int nt = 0; nt < 4; ++nt) {
            float bv = bias[nt * 16 + col];
            baseD[nt] = (f32x4){bv, bv, bv, bv};
        }
        const int nrow = group * 16 + col;
        s16x8 xi0 = frag(nrow, quad * 8), xi1 = frag(nrow, 32 + quad * 8);
        #pragma unroll
        for (int nt = 0; nt < 4; ++nt) {
            baseD[nt] = __builtin_amdgcn_mfma_f32_16x16x32_bf16(xi0, bd[nt][0], baseD[nt], 0, 0, 0);
            baseD[nt] = __builtin_amdgcn_mfma_f32_16x16x32_bf16(xi1, bd[nt][1], baseD[nt], 0, 0, 0);
        }
    }
    int idx[16];
    #pragma unroll
    for (int n = 0; n < 16; ++n) idx[n] = src[group * 256 + n * DEG + col];
    s16x8 xa[3][2];
    #pragma unroll
    for (int p = 0; p < 2; ++p) {
        xa[p][0] = frag(idx[p], quad * 8); xa[p][1] = frag(idx[p], 32 + quad * 8);
    }
    #pragma unroll
    for (int n = 0; n < 16; ++n) {
        if (n + 2 < 16) {
            xa[(n + 2) % 3][0] = frag(idx[n + 2], quad * 8);
            xa[(n + 2) % 3][1] = frag(idx[n + 2], 32 + quad * 8);
        }
        const int slane = ((n >> 2) << 4) | col;
        f32x4 acc[4];
        #pragma unroll
        for (int nt = 0; nt < 4; ++nt) {
            float bb = __shfl(baseD[nt][n & 3], slane);
            acc[nt] = (f32x4){bb, bb, bb, bb};
        }
        #pragma unroll
        for (int nt = 0; nt < 4; ++nt) {
            acc[nt] = __builtin_amdgcn_mfma_f32_16x16x32_bf16(xa[n % 3][0], b2[nt][0], acc[nt], 0, 0, 0);
            acc[nt] = __builtin_amdgcn_mfma_f32_16x16x32_bf16(xa[n % 3][1], b2[nt][1], acc[nt], 0, 0, 0);
        }
        float m[4];
        #pragma unroll
        for (int nt = 0; nt < 4; ++nt) {
            float t = fmaxf(fmaxf(acc[nt][0], acc[nt][1]),
                            fmaxf(acc[nt][2], acc[nt][3]));
            t = fmaxf(t, __shfl_xor(t, 16));
            t = fmaxf(t, __shfl_xor(t, 32));
            m[nt] = t;
        }
        float r = quad == 0 ? m[0] : quad == 1 ? m[1] : quad == 2 ? m[2] : m[3];
        out[(group * 16 + n) * C + lane] = fmaxf(r, 0.0f);
    }
}

extern "C" void kernel_launch(void* const* d_in, const int* in_sizes, int n_in,
                              void* d_out, int out_size, void* d_ws, size_t ws_size,
                              hipStream_t stream) {
    const float* x    = (const float*)d_in[0];
    const int*   src  = (const int*)  d_in[1];   // row 0 of edge_index
    const float* W    = (const float*)d_in[3];
    const float* b    = (const float*)d_in[4];
    float*       out  = (float*)d_out;

    const int n_nodes = in_sizes[0] / C;                 // 50000
    const size_t need = ((size_t)n_nodes * C + 16 * 64 * 8) * sizeof(unsigned short);

    if (ws_size >= need) {
        unsigned short* ws_u = (unsigned short*)d_ws;
        const int n4 = n_nodes * C / 4;                  // 800000
        const int n_groups = (n_nodes + NPW - 1) / NPW;  // 6250
        const int grid = (n_groups + WPB - 1) / WPB;     // 1563
        prep<<<(n4 + 255) / 256, 256, 0, stream>>>(x, W, ws_u, n4);
        edgeconv_mfma<<<grid, 256, 0, stream>>>(ws_u, src, b, out, n_groups, n_nodes);
    } else {
        const int n_groups = (n_nodes + 15) / 16;
        edgeconv_fallback<<<(n_groups + WPB - 1) / WPB, 256, 0, stream>>>(
            x, src, W, b, out, n_groups);
    }
}